// Round 15
// baseline (52.344 us; speedup 1.0000x reference)
//
#include <hip/hip_runtime.h>
#include <hip/hip_bf16.h>

typedef float f32x4 __attribute__((ext_vector_type(4)));
typedef short bf16x8 __attribute__((ext_vector_type(8)));
typedef unsigned short u16;
typedef unsigned int u32;

#define NB 32
#define NN 10000
#define DIMX 64

__device__ __forceinline__ u32 pkbf(float a, float b) {
    __hip_bfloat162 h = __float22bfloat162_rn(make_float2(a, b));
    u32 r; __builtin_memcpy(&r, &h, 4); return r;
}

// ---------------- K1: in-block prep + fused GEMM1(swapped)+GEMM2+reduce ----
// grid = 1024 blocks (b = bid>>5, qb = bid&31), 4 waves/block, 4 blocks/CU.
// Chunks: qb<17 -> 20 subtiles, else 19 (17*20 + 15*19 = 625 = 10000 rows).
// Per-block prep (r11-verified pieces): sW1 fragment-gather from n2e_w,
// w2r regs from e2e_w, bias1 row b via wave-parallel dot, e2e_b + adj -> LDS.
// Main loop = round-13 exactly: 5 iters, GEMM1 (wave's subtile, 4 kk2 slices
// -> sH1 16KB single buffer) / barrier / GEMM2 (4 subtiles x 2 private t2,
// W2 in 32 VGPRs) / barrier / epilogue. acc[4][2] = 32 AGPRs. No fence.
__global__ __launch_bounds__(256, 3) void k_main(
        const float* __restrict__ x, const float* __restrict__ adj,
        const float* __restrict__ n2e_w, const float* __restrict__ n2e_b,
        const float* __restrict__ e2e_w, const float* __restrict__ e2e_b,
        const int* __restrict__ ip,
        float* __restrict__ partials) {
    __shared__ u16 sW1[8192];     // 16 KB packed W1 fragments
    __shared__ u16 sH1[8192];     // 16 KB: [kk2:4][sub:4][512 u16]
    __shared__ float sBias[256];  // [0:128) bias1 row b, [128:256) e2e_b
    __shared__ float sAdj[320];   // chunk adj (zero-padded, 20 subtiles max)

    const int tid = threadIdx.x;
    const int lane = tid & 63, wave = tid >> 6;
    const int c = lane & 15, g = lane >> 4;
    const int bid = blockIdx.x;
    const int b = bid >> 5, qb = bid & 31;
    const int s0 = qb < 17 ? qb * 20 : 340 + (qb - 17) * 19;
    const int cnt = qb < 17 ? 20 : 19;
    const int i0 = ip[0];

    // ---- prep: pack sW1 fragments straight from n2e_w[:, :64] ----
    #pragma unroll
    for (int p = 0; p < 4; ++p) {
        int fp = p * 256 + tid;            // fragment-slot * 64 + lane'
        int f = fp >> 6, ln = fp & 63;
        int t = f >> 1, kk = f & 1;
        int row = t * 16 + (ln & 15), col = kk * 32 + (ln >> 4) * 8;
        const float* src = n2e_w + row * 128 + col;
        f32x4 lo = *(const f32x4*)src, hi = *(const f32x4*)(src + 4);
        union { bf16x8 v; u32 w[4]; } u;
        u.w[0] = pkbf(lo[0], lo[1]); u.w[1] = pkbf(lo[2], lo[3]);
        u.w[2] = pkbf(hi[0], hi[1]); u.w[3] = pkbf(hi[2], hi[3]);
        *(bf16x8*)&sW1[fp * 8] = u.v;
    }
    // ---- prep: W2 fragments for my 2 t2 columns (persistent 32 VGPRs) ----
    bf16x8 w2r[2][4];
    #pragma unroll
    for (int tt = 0; tt < 2; ++tt)
        #pragma unroll
        for (int kk2 = 0; kk2 < 4; ++kk2) {
            int row = (wave * 2 + tt) * 16 + c, col = kk2 * 32 + g * 8;
            const float* src = e2e_w + row * 128 + col;
            f32x4 lo = *(const f32x4*)src, hi = *(const f32x4*)(src + 4);
            union { bf16x8 v; u32 w[4]; } u;
            u.w[0] = pkbf(lo[0], lo[1]); u.w[1] = pkbf(lo[2], lo[3]);
            u.w[2] = pkbf(hi[0], hi[1]); u.w[3] = pkbf(hi[2], hi[3]);
            w2r[tt][kk2] = u.v;
        }
    // ---- prep: bias1 row b, wave-parallel (2 threads per dot) ----
    {
        int j = tid >> 1, half = tid & 1;
        const float* xr = x + ((size_t)b * NN + i0) * DIMX + half * 32;
        const float* w = n2e_w + j * 128 + 64 + half * 32;
        float s = 0.f;
        #pragma unroll 8
        for (int d = 0; d < 32; ++d) s += xr[d] * w[d];
        s += __shfl_xor(s, 1, 64);
        if (!half) sBias[j] = s + n2e_b[j];
    }
    if (tid < 128) sBias[128 + tid] = e2e_b[tid];
    // ---- prep: adj chunk -> LDS (zero-padded) ----
    for (int idx = tid; idx < 320; idx += 256)
        sAdj[idx] = (idx < cnt * 16) ? adj[s0 * 16 + idx] : 0.f;

    float sAcc[2] = {0.f, 0.f};
    __syncthreads();

    const size_t xbatch = (size_t)b * NN;
    const int swzW = 16 * (c & 3);
    const int rdOff = (c * 64 + 16 * (g ^ (c & 3))) >> 1;   // u16 units

    // ---- prefetch iteration 0's x for my subtile ----
    f32x4 xl[4];
    {
        int idx = wave;
        int stl = idx < cnt ? idx : cnt - 1;
        const float* xr = x + (xbatch + (s0 + stl) * 16 + c) * 64 + g * 8;
        xl[0] = *(const f32x4*)(xr);
        xl[1] = *(const f32x4*)(xr + 4);
        xl[2] = *(const f32x4*)(xr + 32);
        xl[3] = *(const f32x4*)(xr + 36);
    }

    #pragma unroll 1
    for (int it = 0; it < 5; ++it) {
        // ---- convert prefetched x to bf16 A-fragments ----
        bf16x8 A1[2];
        #pragma unroll
        for (int kk = 0; kk < 2; ++kk) {
            f32x4 lo = xl[kk * 2], hi = xl[kk * 2 + 1];
            union { bf16x8 v; u32 w[4]; } u;
            u.w[0] = pkbf(lo[0], lo[1]); u.w[1] = pkbf(lo[2], lo[3]);
            u.w[2] = pkbf(hi[0], hi[1]); u.w[3] = pkbf(hi[2], hi[3]);
            A1[kk] = u.v;
        }
        // ---- issue next iteration's x loads (hidden under compute) ----
        if (it < 4) {
            int idx = (it + 1) * 4 + wave;
            int stl = idx < cnt ? idx : cnt - 1;
            const float* xr = x + (xbatch + (s0 + stl) * 16 + c) * 64 + g * 8;
            xl[0] = *(const f32x4*)(xr);
            xl[1] = *(const f32x4*)(xr + 4);
            xl[2] = *(const f32x4*)(xr + 32);
            xl[3] = *(const f32x4*)(xr + 36);
        }

        // ---- GEMM1 phase: my subtile, all 4 kk2 slices ----
        u16* const bufW = &sH1[wave * 512];
        #pragma unroll
        for (int kk2 = 0; kk2 < 4; ++kk2) {
            const int t0 = kk2 * 2, t1 = kk2 * 2 + 1;
            bf16x8 w1a0 = *(const bf16x8*)&sW1[(t0 * 2 + 0) * 512 + lane * 8];
            bf16x8 w1b0 = *(const bf16x8*)&sW1[(t0 * 2 + 1) * 512 + lane * 8];
            bf16x8 w1a1 = *(const bf16x8*)&sW1[(t1 * 2 + 0) * 512 + lane * 8];
            bf16x8 w1b1 = *(const bf16x8*)&sW1[(t1 * 2 + 1) * 512 + lane * 8];
            f32x4 cb0 = *(const f32x4*)&sBias[t0 * 16 + 4 * g];
            f32x4 cb1 = *(const f32x4*)&sBias[t1 * 16 + 4 * g];
            f32x4 d0 = __builtin_amdgcn_mfma_f32_16x16x32_bf16(w1a0, A1[0], cb0, 0, 0, 0);
            d0 = __builtin_amdgcn_mfma_f32_16x16x32_bf16(w1b0, A1[1], d0, 0, 0, 0);
            f32x4 d1 = __builtin_amdgcn_mfma_f32_16x16x32_bf16(w1a1, A1[0], cb1, 0, 0, 0);
            d1 = __builtin_amdgcn_mfma_f32_16x16x32_bf16(w1b1, A1[1], d1, 0, 0, 0);
            u32 p00 = pkbf(fmaxf(d0[0], 0.f), fmaxf(d0[1], 0.f));
            u32 p01 = pkbf(fmaxf(d0[2], 0.f), fmaxf(d0[3], 0.f));
            u32 p10 = pkbf(fmaxf(d1[0], 0.f), fmaxf(d1[1], 0.f));
            u32 p11 = pkbf(fmaxf(d1[2], 0.f), fmaxf(d1[3], 0.f));
            int base = c * 64;
            *(uint2*)&bufW[kk2 * 2048 + ((base + ((8 * g) ^ swzW)) >> 1)]      = make_uint2(p00, p01);
            *(uint2*)&bufW[kk2 * 2048 + ((base + ((32 + 8 * g) ^ swzW)) >> 1)] = make_uint2(p10, p11);
        }
        __syncthreads();   // h1 writes visible

        // ---- GEMM2 phase: all 4 subtiles, my 2 t2 columns ----
        f32x4 acc[4][2];   // 32 AGPRs
        #pragma unroll
        for (int sub = 0; sub < 4; ++sub)
            #pragma unroll
            for (int tt = 0; tt < 2; ++tt) acc[sub][tt] = (f32x4){0.f,0.f,0.f,0.f};
        #pragma unroll
        for (int kk2 = 0; kk2 < 4; ++kk2) {
            bf16x8 A2[4];
            #pragma unroll
            for (int sub = 0; sub < 4; ++sub)
                A2[sub] = *(const bf16x8*)&sH1[kk2 * 2048 + sub * 512 + rdOff];
            #pragma unroll
            for (int tt = 0; tt < 2; ++tt)
                #pragma unroll
                for (int sub = 0; sub < 4; ++sub)
                    acc[sub][tt] = __builtin_amdgcn_mfma_f32_16x16x32_bf16(A2[sub], w2r[tt][kk2], acc[sub][tt], 0, 0, 0);
        }
        __syncthreads();   // reads done before next iteration's writes

        // ---- epilogue: adj (from LDS) + bias2 + relu, weighted row sum ----
        #pragma unroll
        for (int tt = 0; tt < 2; ++tt) {
            float bb = sBias[128 + (wave * 2 + tt) * 16 + c];
            #pragma unroll
            for (int sub = 0; sub < 4; ++sub) {
                f32x4 av = *(const f32x4*)&sAdj[(it * 4 + sub) * 16 + 4 * g];
                #pragma unroll
                for (int r = 0; r < 4; ++r)
                    sAcc[tt] = fmaf(av[r], fmaxf(acc[sub][tt][r] + bb, 0.f), sAcc[tt]);
            }
        }
    }

    // ---- reduce over lane-groups (g); direct partials write ----
    float red[2];
    #pragma unroll
    for (int tt = 0; tt < 2; ++tt) {
        float v = sAcc[tt];
        v += __shfl_xor(v, 16, 64);
        v += __shfl_xor(v, 32, 64);
        red[tt] = v;
    }
    if (lane < 16) {
        #pragma unroll
        for (int tt = 0; tt < 2; ++tt)
            partials[bid * 128 + (wave * 2 + tt) * 16 + lane] = red[tt];
    }
}

// ---------------- K2: final small MLP ----------------
__global__ void k_final(const float* __restrict__ partials, const float* __restrict__ x,
                        const int* __restrict__ ip,
                        const float* __restrict__ e2n_w, const float* __restrict__ e2n_b,
                        const float* __restrict__ n2n_w, const float* __restrict__ n2n_b,
                        const float* __restrict__ out_w, const float* __restrict__ out_b,
                        float* __restrict__ out) {
    int b = blockIdx.x, j = threadIdx.x;  // 128 threads
    __shared__ float s0[128], s1[128], s2[128];
    float acc = 0.f;
    #pragma unroll
    for (int qq = 0; qq < 32; ++qq) acc += partials[(b * 32 + qq) * 128 + j];
    s0[j] = acc;
    __syncthreads();
    {
        float a1 = e2n_b[j];
        const float* w = e2n_w + j * 128;
        #pragma unroll 8
        for (int k = 0; k < 128; ++k) a1 += w[k] * s0[k];
        s1[j] = fmaxf(a1, 0.f);
    }
    __syncthreads();
    {
        float a2 = n2n_b[j];
        const float* w = n2n_w + j * 128;
        #pragma unroll 8
        for (int k = 0; k < 128; ++k) a2 += w[k] * s1[k];
        s2[j] = fmaxf(a2, 0.f);
    }
    __syncthreads();
    if (j < 64) {
        int i = ip[0];
        const float* xr = x + ((size_t)b * NN + i) * DIMX;
        const float* ow = out_w + j * 192;
        float o = out_b[j];
        #pragma unroll 8
        for (int m = 0; m < 64; ++m) o += ow[m] * xr[m];
        #pragma unroll 8
        for (int m = 0; m < 128; ++m) o += ow[64 + m] * s2[m];
        out[b * 64 + j] = o;
    }
}

extern "C" void kernel_launch(void* const* d_in, const int* in_sizes, int n_in,
                              void* d_out, int out_size, void* d_ws, size_t ws_size,
                              hipStream_t stream) {
    const float* x      = (const float*)d_in[0];
    const float* adj    = (const float*)d_in[1];
    const float* n2e_w  = (const float*)d_in[2];
    const float* n2e_b  = (const float*)d_in[3];
    const float* e2e_w  = (const float*)d_in[4];
    const float* e2e_b  = (const float*)d_in[5];
    const float* e2n_w  = (const float*)d_in[6];
    const float* e2n_b  = (const float*)d_in[7];
    const float* n2n_w  = (const float*)d_in[8];
    const float* n2n_b  = (const float*)d_in[9];
    const float* out_w  = (const float*)d_in[10];
    const float* out_b  = (const float*)d_in[11];
    const int*   ip     = (const int*)d_in[12];
    float* out = (float*)d_out;

    float* partials = (float*)d_ws;             // 524288 B (1024 blocks * 128 f32)

    k_main<<<1024, 256, 0, stream>>>(x, adj, n2e_w, n2e_b, e2e_w, e2e_b,
                                     ip, partials);
    k_final<<<32, 128, 0, stream>>>(partials, x, ip, e2n_w, e2n_b, n2n_w, n2n_b,
                                    out_w, out_b, out);
}

// Round 16
// 43.581 us; speedup vs baseline: 1.2011x; 1.2011x over previous
//
#include <hip/hip_runtime.h>
#include <hip/hip_bf16.h>

typedef float f32x4 __attribute__((ext_vector_type(4)));
typedef short bf16x8 __attribute__((ext_vector_type(8)));
typedef unsigned short u16;
typedef unsigned int u32;

#define NB 32
#define NN 10000
#define DIMX 64

__device__ __forceinline__ u16 f2bf(float f) {
    union { float f; unsigned u; } v; v.f = f;
    unsigned r = (v.u + 0x7FFFu + ((v.u >> 16) & 1u)) >> 16;
    return (u16)r;
}

__device__ __forceinline__ u32 pkbf(float a, float b) {
    __hip_bfloat162 h = __float22bfloat162_rn(make_float2(a, b));
    u32 r; __builtin_memcpy(&r, &h, 4); return r;
}

// ---------------- K1: prep (ws-packed weights + bias1) ----------------
__global__ void k_prep(const float* __restrict__ x, const float* __restrict__ n2e_w,
                       const float* __restrict__ n2e_b, const float* __restrict__ e2e_w,
                       const int* __restrict__ ip,
                       float* __restrict__ bias1, u16* __restrict__ w1p, u16* __restrict__ w2p) {
    int id = blockIdx.x * 256 + threadIdx.x;
    if (id < 4096) {
        int b = id >> 7, j = id & 127;
        int i = ip[0];
        const float* xr = x + ((size_t)b * NN + i) * DIMX;
        const float* w = n2e_w + j * 128 + 64;
        float s = n2e_b[j];
        #pragma unroll
        for (int d = 0; d < 64; ++d) s += xr[d] * w[d];
        bias1[b * 128 + j] = s;
    } else if (id < 12288) {
        int e = id - 4096;
        int i8 = e & 7, lane = (e >> 3) & 63, kk = (e >> 9) & 1, t = e >> 10;
        int row = t * 16 + (lane & 15), col = kk * 32 + (lane >> 4) * 8 + i8;
        w1p[e] = f2bf(n2e_w[row * 128 + col]);
    } else if (id < 28672) {
        int e = id - 12288;
        int i8 = e & 7, lane = (e >> 3) & 63, kk = (e >> 9) & 3, t = e >> 11;
        int row = t * 16 + (lane & 15), col = kk * 32 + (lane >> 4) * 8 + i8;
        w2p[e] = f2bf(e2e_w[row * 128 + col]);
    }
}

// ---------------- K2: main, t-split GEMM1 + x-through-LDS ----------------
// grid = 1024 blocks (b = bid>>5, qb = bid&31), 4 waves/block, 4 blocks/CU.
// Chunks: qb<17 -> 20 subtiles, else 19 (17*20 + 15*19 = 625 = 10000 rows).
// Per iteration (4 subtiles):
//   1. wave converts its prefetched x subtile -> sX[par][wave] (2 b128 wr)
//   2. issue next-iter x prefetch
//   3. barrier (x visible)
//   4. GEMM1: wave w owns t-pair {2w,2w+1} == slice kk2=w; W1 frags + bias
//      in REGISTERS; for sub 0..3: read A1 from sX, 4 MFMA, pack, write
//      sH1[w][sub]
//   5. barrier (h1 visible)
//   6. GEMM2: r13 unchanged (4 kk2 x 4 A2 reads + 8 MFMA, W2 in 32 VGPRs)
//   7. epilogue; par ^= 1
// WAR safety: sX parity + (writes sH1 at 4' only after barrier 3', which
// orders them after all GEMM2 reads of iter i). LDS 34.3 KB -> 4 blocks/CU.
__global__ __launch_bounds__(256, 3) void k_main(
        const float* __restrict__ x, const float* __restrict__ adj,
        const float* __restrict__ bias1, const u16* __restrict__ w1p,
        const u16* __restrict__ w2p, const float* __restrict__ e2e_b,
        float* __restrict__ partials) {
    __shared__ u16 sX[8192];      // 16 KB: [par2][sub4][kk2][64][8]
    __shared__ u16 sH1[8192];     // 16 KB: [kk2:4][sub:4][512 u16]
    __shared__ float sBias[128];  // bias1 row b
    __shared__ float sAdj[320];   // chunk adj (zero-padded, 20 subtiles max)

    const int tid = threadIdx.x;
    const int lane = tid & 63, wave = tid >> 6;
    const int c = lane & 15, g = lane >> 4;
    const int bid = blockIdx.x;
    const int b = bid >> 5, qb = bid & 31;
    const int s0 = qb < 17 ? qb * 20 : 340 + (qb - 17) * 19;
    const int cnt = qb < 17 ? 20 : 19;

    if (tid < 128) sBias[tid] = bias1[b * 128 + tid];
    for (int idx = tid; idx < 320; idx += 256)
        sAdj[idx] = (idx < cnt * 16) ? adj[s0 * 16 + idx] : 0.f;

    // W1 fragments for my t-pair {2w, 2w+1} (16 VGPRs, from packed global)
    const bf16x8* const gW1 = (const bf16x8*)w1p;
    const bf16x8 w1a0 = gW1[(wave * 4 + 0) * 64 + lane];
    const bf16x8 w1b0 = gW1[(wave * 4 + 1) * 64 + lane];
    const bf16x8 w1a1 = gW1[(wave * 4 + 2) * 64 + lane];
    const bf16x8 w1b1 = gW1[(wave * 4 + 3) * 64 + lane];
    // W2 fragments for my 2 t2 columns (32 VGPRs)
    const bf16x8* const gW2 = (const bf16x8*)w2p;
    bf16x8 w2r[2][4];
    #pragma unroll
    for (int tt = 0; tt < 2; ++tt)
        #pragma unroll
        for (int kk2 = 0; kk2 < 4; ++kk2)
            w2r[tt][kk2] = gW2[((wave * 2 + tt) * 4 + kk2) * 64 + lane];
    // epilogue bias for my 2 t2 columns (2 regs)
    const float b2v0 = e2e_b[(wave * 2 + 0) * 16 + c];
    const float b2v1 = e2e_b[(wave * 2 + 1) * 16 + c];

    float sAcc[2] = {0.f, 0.f};
    __syncthreads();

    // bias (C-operand) for my t-pair, from LDS after barrier (8 regs)
    const f32x4 cb0 = *(const f32x4*)&sBias[(wave * 2 + 0) * 16 + 4 * g];
    const f32x4 cb1 = *(const f32x4*)&sBias[(wave * 2 + 1) * 16 + 4 * g];

    const size_t xbatch = (size_t)b * NN;
    const int swzW = 16 * (c & 3);
    const int rdOff = (c * 64 + 16 * (g ^ (c & 3))) >> 1;   // u16 units

    // ---- prefetch iteration 0's x for my subtile ----
    f32x4 xl[4];
    {
        int idx = wave;
        int stl = idx < cnt ? idx : cnt - 1;
        const float* xr = x + (xbatch + (s0 + stl) * 16 + c) * 64 + g * 8;
        xl[0] = *(const f32x4*)(xr);
        xl[1] = *(const f32x4*)(xr + 4);
        xl[2] = *(const f32x4*)(xr + 32);
        xl[3] = *(const f32x4*)(xr + 36);
    }

    int par = 0;
    #pragma unroll 1
    for (int it = 0; it < 5; ++it) {
        // ---- 1. convert prefetched x -> sX[par][wave] ----
        #pragma unroll
        for (int kk = 0; kk < 2; ++kk) {
            f32x4 lo = xl[kk * 2], hi = xl[kk * 2 + 1];
            union { bf16x8 v; u32 w[4]; } u;
            u.w[0] = pkbf(lo[0], lo[1]); u.w[1] = pkbf(lo[2], lo[3]);
            u.w[2] = pkbf(hi[0], hi[1]); u.w[3] = pkbf(hi[2], hi[3]);
            *(bf16x8*)&sX[(((par * 4 + wave) * 2 + kk) * 64 + lane) * 8] = u.v;
        }
        // ---- 2. issue next iteration's x loads ----
        if (it < 4) {
            int idx = (it + 1) * 4 + wave;
            int stl = idx < cnt ? idx : cnt - 1;
            const float* xr = x + (xbatch + (s0 + stl) * 16 + c) * 64 + g * 8;
            xl[0] = *(const f32x4*)(xr);
            xl[1] = *(const f32x4*)(xr + 4);
            xl[2] = *(const f32x4*)(xr + 32);
            xl[3] = *(const f32x4*)(xr + 36);
        }
        __syncthreads();   // 3. x visible

        // ---- 4. GEMM1: my t-pair (slice kk2 == wave), all 4 subtiles ----
        u16* const bufW = &sH1[wave * 2048];
        #pragma unroll
        for (int sub = 0; sub < 4; ++sub) {
            bf16x8 A10 = *(const bf16x8*)&sX[(((par * 4 + sub) * 2 + 0) * 64 + lane) * 8];
            bf16x8 A11 = *(const bf16x8*)&sX[(((par * 4 + sub) * 2 + 1) * 64 + lane) * 8];
            f32x4 d0 = __builtin_amdgcn_mfma_f32_16x16x32_bf16(w1a0, A10, cb0, 0, 0, 0);
            d0 = __builtin_amdgcn_mfma_f32_16x16x32_bf16(w1b0, A11, d0, 0, 0, 0);
            f32x4 d1 = __builtin_amdgcn_mfma_f32_16x16x32_bf16(w1a1, A10, cb1, 0, 0, 0);
            d1 = __builtin_amdgcn_mfma_f32_16x16x32_bf16(w1b1, A11, d1, 0, 0, 0);
            u32 p00 = pkbf(fmaxf(d0[0], 0.f), fmaxf(d0[1], 0.f));
            u32 p01 = pkbf(fmaxf(d0[2], 0.f), fmaxf(d0[3], 0.f));
            u32 p10 = pkbf(fmaxf(d1[0], 0.f), fmaxf(d1[1], 0.f));
            u32 p11 = pkbf(fmaxf(d1[2], 0.f), fmaxf(d1[3], 0.f));
            int base = c * 64;
            *(uint2*)&bufW[sub * 512 + ((base + ((8 * g) ^ swzW)) >> 1)]      = make_uint2(p00, p01);
            *(uint2*)&bufW[sub * 512 + ((base + ((32 + 8 * g) ^ swzW)) >> 1)] = make_uint2(p10, p11);
        }
        __syncthreads();   // 5. h1 visible

        // ---- 6. GEMM2: all 4 subtiles, my 2 t2 columns ----
        f32x4 acc[4][2];   // 32 AGPRs
        #pragma unroll
        for (int sub = 0; sub < 4; ++sub)
            #pragma unroll
            for (int tt = 0; tt < 2; ++tt) acc[sub][tt] = (f32x4){0.f,0.f,0.f,0.f};
        #pragma unroll
        for (int kk2 = 0; kk2 < 4; ++kk2) {
            bf16x8 A2[4];
            #pragma unroll
            for (int sub = 0; sub < 4; ++sub)
                A2[sub] = *(const bf16x8*)&sH1[kk2 * 2048 + sub * 512 + rdOff];
            #pragma unroll
            for (int tt = 0; tt < 2; ++tt)
                #pragma unroll
                for (int sub = 0; sub < 4; ++sub)
                    acc[sub][tt] = __builtin_amdgcn_mfma_f32_16x16x32_bf16(A2[sub], w2r[tt][kk2], acc[sub][tt], 0, 0, 0);
        }

        // ---- 7. epilogue: adj + bias2 + relu, weighted row sum ----
        #pragma unroll
        for (int sub = 0; sub < 4; ++sub) {
            f32x4 av = *(const f32x4*)&sAdj[(it * 4 + sub) * 16 + 4 * g];
            #pragma unroll
            for (int r = 0; r < 4; ++r) {
                sAcc[0] = fmaf(av[r], fmaxf(acc[sub][0][r] + b2v0, 0.f), sAcc[0]);
                sAcc[1] = fmaf(av[r], fmaxf(acc[sub][1][r] + b2v1, 0.f), sAcc[1]);
            }
        }
        par ^= 1;
    }

    // ---- reduce over lane-groups (g); direct partials write ----
    float red[2];
    #pragma unroll
    for (int tt = 0; tt < 2; ++tt) {
        float v = sAcc[tt];
        v += __shfl_xor(v, 16, 64);
        v += __shfl_xor(v, 32, 64);
        red[tt] = v;
    }
    if (lane < 16) {
        #pragma unroll
        for (int tt = 0; tt < 2; ++tt)
            partials[bid * 128 + (wave * 2 + tt) * 16 + lane] = red[tt];
    }
}

// ---------------- K3: final small MLP ----------------
__global__ void k_final(const float* __restrict__ partials, const float* __restrict__ x,
                        const int* __restrict__ ip,
                        const float* __restrict__ e2n_w, const float* __restrict__ e2n_b,
                        const float* __restrict__ n2n_w, const float* __restrict__ n2n_b,
                        const float* __restrict__ out_w, const float* __restrict__ out_b,
                        float* __restrict__ out) {
    int b = blockIdx.x, j = threadIdx.x;  // 128 threads
    __shared__ float s0[128], s1[128], s2[128];
    float acc = 0.f;
    #pragma unroll
    for (int qq = 0; qq < 32; ++qq) acc += partials[(b * 32 + qq) * 128 + j];
    s0[j] = acc;
    __syncthreads();
    {
        float a1 = e2n_b[j];
        const float* w = e2n_w + j * 128;
        #pragma unroll 8
        for (int k = 0; k < 128; ++k) a1 += w[k] * s0[k];
        s1[j] = fmaxf(a1, 0.f);
    }
    __syncthreads();
    {
        float a2 = n2n_b[j];
        const float* w = n2n_w + j * 128;
        #pragma unroll 8
        for (int k = 0; k < 128; ++k) a2 += w[k] * s1[k];
        s2[j] = fmaxf(a2, 0.f);
    }
    __syncthreads();
    if (j < 64) {
        int i = ip[0];
        const float* xr = x + ((size_t)b * NN + i) * DIMX;
        const float* ow = out_w + j * 192;
        float o = out_b[j];
        #pragma unroll 8
        for (int m = 0; m < 64; ++m) o += ow[m] * xr[m];
        #pragma unroll 8
        for (int m = 0; m < 128; ++m) o += ow[64 + m] * s2[m];
        out[b * 64 + j] = o;
    }
}

extern "C" void kernel_launch(void* const* d_in, const int* in_sizes, int n_in,
                              void* d_out, int out_size, void* d_ws, size_t ws_size,
                              hipStream_t stream) {
    const float* x      = (const float*)d_in[0];
    const float* adj    = (const float*)d_in[1];
    const float* n2e_w  = (const float*)d_in[2];
    const float* n2e_b  = (const float*)d_in[3];
    const float* e2e_w  = (const float*)d_in[4];
    const float* e2e_b  = (const float*)d_in[5];
    const float* e2n_w  = (const float*)d_in[6];
    const float* e2n_b  = (const float*)d_in[7];
    const float* n2n_w  = (const float*)d_in[8];
    const float* n2n_b  = (const float*)d_in[9];
    const float* out_w  = (const float*)d_in[10];
    const float* out_b  = (const float*)d_in[11];
    const int*   ip     = (const int*)d_in[12];
    float* out = (float*)d_out;

    char* ws = (char*)d_ws;
    float* bias1    = (float*)ws;               // 16384 B
    u16*   w1p      = (u16*)(ws + 16384);       // 16384 B
    u16*   w2p      = (u16*)(ws + 32768);       // 32768 B
    float* partials = (float*)(ws + 65536);     // 524288 B (1024 blocks * 128 f32)

    k_prep<<<112, 256, 0, stream>>>(x, n2e_w, n2e_b, e2e_w, ip, bias1, w1p, w2p);
    k_main<<<1024, 256, 0, stream>>>(x, adj, bias1, w1p, w2p, e2e_b, partials);
    k_final<<<32, 128, 0, stream>>>(partials, x, ip, e2n_w, e2n_b, n2n_w, n2n_b,
                                    out_w, out_b, out);
}

// Round 17
// 42.702 us; speedup vs baseline: 1.2258x; 1.0206x over previous
//
#include <hip/hip_runtime.h>
#include <hip/hip_bf16.h>

typedef float f32x4 __attribute__((ext_vector_type(4)));
typedef short bf16x8 __attribute__((ext_vector_type(8)));
typedef unsigned short u16;
typedef unsigned int u32;

#define NB 32
#define NN 10000
#define DIMX 64

__device__ __forceinline__ u16 f2bf(float f) {
    union { float f; unsigned u; } v; v.f = f;
    unsigned r = (v.u + 0x7FFFu + ((v.u >> 16) & 1u)) >> 16;
    return (u16)r;
}

__device__ __forceinline__ u32 pkbf(float a, float b) {
    __hip_bfloat162 h = __float22bfloat162_rn(make_float2(a, b));
    u32 r; __builtin_memcpy(&r, &h, 4); return r;
}

// ---------------- K1: prep (ws-packed weights + bias1, vectorized) --------
// grid = 128 blocks x 256. id<8192: bias1 (2 threads per (b,j), f32x4 loads,
// shfl combine). 8192..16384: w1p pack. 16384..32768: w2p pack.
__global__ void k_prep(const float* __restrict__ x, const float* __restrict__ n2e_w,
                       const float* __restrict__ n2e_b, const float* __restrict__ e2e_w,
                       const int* __restrict__ ip,
                       float* __restrict__ bias1, u16* __restrict__ w1p, u16* __restrict__ w2p) {
    int id = blockIdx.x * 256 + threadIdx.x;
    if (id < 8192) {
        int pair = id >> 1, half = id & 1;
        int b = pair >> 7, j = pair & 127;
        int i = ip[0];
        const f32x4* xr = (const f32x4*)(x + ((size_t)b * NN + i) * DIMX + half * 32);
        const f32x4* w  = (const f32x4*)(n2e_w + j * 128 + 64 + half * 32);
        float s = 0.f;
        #pragma unroll
        for (int kv = 0; kv < 8; ++kv) {
            f32x4 a = xr[kv], bb = w[kv];
            s += a[0] * bb[0] + a[1] * bb[1] + a[2] * bb[2] + a[3] * bb[3];
        }
        s += __shfl_xor(s, 1, 64);
        if (!half) bias1[b * 128 + j] = s + n2e_b[j];
    } else if (id < 16384) {
        int e = id - 8192;
        int i8 = e & 7, lane = (e >> 3) & 63, kk = (e >> 9) & 1, t = e >> 10;
        int row = t * 16 + (lane & 15), col = kk * 32 + (lane >> 4) * 8 + i8;
        w1p[e] = f2bf(n2e_w[row * 128 + col]);
    } else {
        int e = id - 16384;
        int i8 = e & 7, lane = (e >> 3) & 63, kk = (e >> 9) & 3, t = e >> 11;
        int row = t * 16 + (lane & 15), col = kk * 32 + (lane >> 4) * 8 + i8;
        w2p[e] = f2bf(e2e_w[row * 128 + col]);
    }
}

// ---------------- K2: main, t-split GEMM1 + x-through-LDS (r16 exact) -----
__global__ __launch_bounds__(256, 3) void k_main(
        const float* __restrict__ x, const float* __restrict__ adj,
        const float* __restrict__ bias1, const u16* __restrict__ w1p,
        const u16* __restrict__ w2p, const float* __restrict__ e2e_b,
        float* __restrict__ partials) {
    __shared__ u16 sX[8192];      // 16 KB: [par2][sub4][kk2][64][8]
    __shared__ u16 sH1[8192];     // 16 KB: [kk2:4][sub:4][512 u16]
    __shared__ float sBias[128];  // bias1 row b
    __shared__ float sAdj[320];   // chunk adj (zero-padded, 20 subtiles max)

    const int tid = threadIdx.x;
    const int lane = tid & 63, wave = tid >> 6;
    const int c = lane & 15, g = lane >> 4;
    const int bid = blockIdx.x;
    const int b = bid >> 5, qb = bid & 31;
    const int s0 = qb < 17 ? qb * 20 : 340 + (qb - 17) * 19;
    const int cnt = qb < 17 ? 20 : 19;

    if (tid < 128) sBias[tid] = bias1[b * 128 + tid];
    for (int idx = tid; idx < 320; idx += 256)
        sAdj[idx] = (idx < cnt * 16) ? adj[s0 * 16 + idx] : 0.f;

    // W1 fragments for my t-pair {2w, 2w+1} (16 VGPRs, from packed global)
    const bf16x8* const gW1 = (const bf16x8*)w1p;
    const bf16x8 w1a0 = gW1[(wave * 4 + 0) * 64 + lane];
    const bf16x8 w1b0 = gW1[(wave * 4 + 1) * 64 + lane];
    const bf16x8 w1a1 = gW1[(wave * 4 + 2) * 64 + lane];
    const bf16x8 w1b1 = gW1[(wave * 4 + 3) * 64 + lane];
    // W2 fragments for my 2 t2 columns (32 VGPRs)
    const bf16x8* const gW2 = (const bf16x8*)w2p;
    bf16x8 w2r[2][4];
    #pragma unroll
    for (int tt = 0; tt < 2; ++tt)
        #pragma unroll
        for (int kk2 = 0; kk2 < 4; ++kk2)
            w2r[tt][kk2] = gW2[((wave * 2 + tt) * 4 + kk2) * 64 + lane];
    // epilogue bias for my 2 t2 columns (2 regs)
    const float b2v0 = e2e_b[(wave * 2 + 0) * 16 + c];
    const float b2v1 = e2e_b[(wave * 2 + 1) * 16 + c];

    float sAcc[2] = {0.f, 0.f};
    __syncthreads();

    // bias (C-operand) for my t-pair, from LDS after barrier (8 regs)
    const f32x4 cb0 = *(const f32x4*)&sBias[(wave * 2 + 0) * 16 + 4 * g];
    const f32x4 cb1 = *(const f32x4*)&sBias[(wave * 2 + 1) * 16 + 4 * g];

    const size_t xbatch = (size_t)b * NN;
    const int swzW = 16 * (c & 3);
    const int rdOff = (c * 64 + 16 * (g ^ (c & 3))) >> 1;   // u16 units

    // ---- prefetch iteration 0's x for my subtile ----
    f32x4 xl[4];
    {
        int idx = wave;
        int stl = idx < cnt ? idx : cnt - 1;
        const float* xr = x + (xbatch + (s0 + stl) * 16 + c) * 64 + g * 8;
        xl[0] = *(const f32x4*)(xr);
        xl[1] = *(const f32x4*)(xr + 4);
        xl[2] = *(const f32x4*)(xr + 32);
        xl[3] = *(const f32x4*)(xr + 36);
    }

    int par = 0;
    #pragma unroll 1
    for (int it = 0; it < 5; ++it) {
        // ---- 1. convert prefetched x -> sX[par][wave] ----
        #pragma unroll
        for (int kk = 0; kk < 2; ++kk) {
            f32x4 lo = xl[kk * 2], hi = xl[kk * 2 + 1];
            union { bf16x8 v; u32 w[4]; } u;
            u.w[0] = pkbf(lo[0], lo[1]); u.w[1] = pkbf(lo[2], lo[3]);
            u.w[2] = pkbf(hi[0], hi[1]); u.w[3] = pkbf(hi[2], hi[3]);
            *(bf16x8*)&sX[(((par * 4 + wave) * 2 + kk) * 64 + lane) * 8] = u.v;
        }
        // ---- 2. issue next iteration's x loads ----
        if (it < 4) {
            int idx = (it + 1) * 4 + wave;
            int stl = idx < cnt ? idx : cnt - 1;
            const float* xr = x + (xbatch + (s0 + stl) * 16 + c) * 64 + g * 8;
            xl[0] = *(const f32x4*)(xr);
            xl[1] = *(const f32x4*)(xr + 4);
            xl[2] = *(const f32x4*)(xr + 32);
            xl[3] = *(const f32x4*)(xr + 36);
        }
        __syncthreads();   // 3. x visible

        // ---- 4. GEMM1: my t-pair (slice kk2 == wave), all 4 subtiles ----
        u16* const bufW = &sH1[wave * 2048];
        #pragma unroll
        for (int sub = 0; sub < 4; ++sub) {
            bf16x8 A10 = *(const bf16x8*)&sX[(((par * 4 + sub) * 2 + 0) * 64 + lane) * 8];
            bf16x8 A11 = *(const bf16x8*)&sX[(((par * 4 + sub) * 2 + 1) * 64 + lane) * 8];
            f32x4 d0 = __builtin_amdgcn_mfma_f32_16x16x32_bf16(w1a0, A10, cb0, 0, 0, 0);
            d0 = __builtin_amdgcn_mfma_f32_16x16x32_bf16(w1b0, A11, d0, 0, 0, 0);
            f32x4 d1 = __builtin_amdgcn_mfma_f32_16x16x32_bf16(w1a1, A10, cb1, 0, 0, 0);
            d1 = __builtin_amdgcn_mfma_f32_16x16x32_bf16(w1b1, A11, d1, 0, 0, 0);
            u32 p00 = pkbf(fmaxf(d0[0], 0.f), fmaxf(d0[1], 0.f));
            u32 p01 = pkbf(fmaxf(d0[2], 0.f), fmaxf(d0[3], 0.f));
            u32 p10 = pkbf(fmaxf(d1[0], 0.f), fmaxf(d1[1], 0.f));
            u32 p11 = pkbf(fmaxf(d1[2], 0.f), fmaxf(d1[3], 0.f));
            int base = c * 64;
            *(uint2*)&bufW[sub * 512 + ((base + ((8 * g) ^ swzW)) >> 1)]      = make_uint2(p00, p01);
            *(uint2*)&bufW[sub * 512 + ((base + ((32 + 8 * g) ^ swzW)) >> 1)] = make_uint2(p10, p11);
        }
        __syncthreads();   // 5. h1 visible

        // ---- 6. GEMM2: all 4 subtiles, my 2 t2 columns ----
        f32x4 acc[4][2];   // 32 AGPRs
        #pragma unroll
        for (int sub = 0; sub < 4; ++sub)
            #pragma unroll
            for (int tt = 0; tt < 2; ++tt) acc[sub][tt] = (f32x4){0.f,0.f,0.f,0.f};
        #pragma unroll
        for (int kk2 = 0; kk2 < 4; ++kk2) {
            bf16x8 A2[4];
            #pragma unroll
            for (int sub = 0; sub < 4; ++sub)
                A2[sub] = *(const bf16x8*)&sH1[kk2 * 2048 + sub * 512 + rdOff];
            #pragma unroll
            for (int tt = 0; tt < 2; ++tt)
                #pragma unroll
                for (int sub = 0; sub < 4; ++sub)
                    acc[sub][tt] = __builtin_amdgcn_mfma_f32_16x16x32_bf16(A2[sub], w2r[tt][kk2], acc[sub][tt], 0, 0, 0);
        }

        // ---- 7. epilogue: adj + bias2 + relu, weighted row sum ----
        #pragma unroll
        for (int sub = 0; sub < 4; ++sub) {
            f32x4 av = *(const f32x4*)&sAdj[(it * 4 + sub) * 16 + 4 * g];
            #pragma unroll
            for (int r = 0; r < 4; ++r) {
                sAcc[0] = fmaf(av[r], fmaxf(acc[sub][0][r] + b2v0, 0.f), sAcc[0]);
                sAcc[1] = fmaf(av[r], fmaxf(acc[sub][1][r] + b2v1, 0.f), sAcc[1]);
            }
        }
        par ^= 1;
    }

    // ---- reduce over lane-groups (g); direct partials write ----
    float red[2];
    #pragma unroll
    for (int tt = 0; tt < 2; ++tt) {
        float v = sAcc[tt];
        v += __shfl_xor(v, 16, 64);
        v += __shfl_xor(v, 32, 64);
        red[tt] = v;
    }
    if (lane < 16) {
        #pragma unroll
        for (int tt = 0; tt < 2; ++tt)
            partials[bid * 128 + (wave * 2 + tt) * 16 + lane] = red[tt];
    }
}

// ---------------- K3: final small MLP (256 threads, 2-way split dots) -----
__global__ void k_final(const float* __restrict__ partials, const float* __restrict__ x,
                        const int* __restrict__ ip,
                        const float* __restrict__ e2n_w, const float* __restrict__ e2n_b,
                        const float* __restrict__ n2n_w, const float* __restrict__ n2n_b,
                        const float* __restrict__ out_w, const float* __restrict__ out_b,
                        float* __restrict__ out) {
    int b = blockIdx.x, t = threadIdx.x;
    int j = t >> 1, half = t & 1;
    __shared__ float s0[128], s1[128], s2[128];

    // partial sums: 16 qq each, shfl-combined
    float a0 = 0.f;
    #pragma unroll
    for (int q = 0; q < 16; ++q)
        a0 += partials[(b * 32 + half * 16 + q) * 128 + j];
    a0 += __shfl_xor(a0, 1, 64);
    if (!half) s0[j] = a0;
    __syncthreads();
    {
        const f32x4* w  = (const f32x4*)(e2n_w + j * 128 + half * 64);
        const f32x4* sv = (const f32x4*)(s0 + half * 64);
        float a1 = 0.f;
        #pragma unroll
        for (int k = 0; k < 16; ++k) {
            f32x4 wv = w[k], s4 = sv[k];
            a1 += wv[0] * s4[0] + wv[1] * s4[1] + wv[2] * s4[2] + wv[3] * s4[3];
        }
        a1 += __shfl_xor(a1, 1, 64);
        if (!half) s1[j] = fmaxf(a1 + e2n_b[j], 0.f);
    }
    __syncthreads();
    {
        const f32x4* w  = (const f32x4*)(n2n_w + j * 128 + half * 64);
        const f32x4* sv = (const f32x4*)(s1 + half * 64);
        float a2 = 0.f;
        #pragma unroll
        for (int k = 0; k < 16; ++k) {
            f32x4 wv = w[k], s4 = sv[k];
            a2 += wv[0] * s4[0] + wv[1] * s4[1] + wv[2] * s4[2] + wv[3] * s4[3];
        }
        a2 += __shfl_xor(a2, 1, 64);
        if (!half) s2[j] = fmaxf(a2 + n2n_b[j], 0.f);
    }
    __syncthreads();
    if (j < 64) {
        int i = ip[0];
        const float* xr = x + ((size_t)b * NN + i) * DIMX;
        const float* ow = out_w + j * 192;
        float o = 0.f;
        if (!half) {
            #pragma unroll 8
            for (int m = 0; m < 64; ++m) o += ow[m] * xr[m];
            #pragma unroll 8
            for (int m = 0; m < 32; ++m) o += ow[64 + m] * s2[m];
        } else {
            #pragma unroll 8
            for (int m = 32; m < 128; ++m) o += ow[64 + m] * s2[m];
        }
        o += __shfl_xor(o, 1, 64);
        if (!half) out[b * 64 + j] = o + out_b[j];
    }
}

extern "C" void kernel_launch(void* const* d_in, const int* in_sizes, int n_in,
                              void* d_out, int out_size, void* d_ws, size_t ws_size,
                              hipStream_t stream) {
    const float* x      = (const float*)d_in[0];
    const float* adj    = (const float*)d_in[1];
    const float* n2e_w  = (const float*)d_in[2];
    const float* n2e_b  = (const float*)d_in[3];
    const float* e2e_w  = (const float*)d_in[4];
    const float* e2e_b  = (const float*)d_in[5];
    const float* e2n_w  = (const float*)d_in[6];
    const float* e2n_b  = (const float*)d_in[7];
    const float* n2n_w  = (const float*)d_in[8];
    const float* n2n_b  = (const float*)d_in[9];
    const float* out_w  = (const float*)d_in[10];
    const float* out_b  = (const float*)d_in[11];
    const int*   ip     = (const int*)d_in[12];
    float* out = (float*)d_out;

    char* ws = (char*)d_ws;
    float* bias1    = (float*)ws;               // 16384 B
    u16*   w1p      = (u16*)(ws + 16384);       // 16384 B
    u16*   w2p      = (u16*)(ws + 32768);       // 32768 B
    float* partials = (float*)(ws + 65536);     // 524288 B (1024 blocks * 128 f32)

    k_prep<<<128, 256, 0, stream>>>(x, n2e_w, n2e_b, e2e_w, ip, bias1, w1p, w2p);
    k_main<<<1024, 256, 0, stream>>>(x, adj, bias1, w1p, w2p, e2e_b, partials);
    k_final<<<32, 256, 0, stream>>>(partials, x, ip, e2n_w, e2n_b, n2n_w, n2n_b,
                                    out_w, out_b, out);
}

// Round 18
// 42.238 us; speedup vs baseline: 1.2392x; 1.0110x over previous
//
#include <hip/hip_runtime.h>
#include <hip/hip_bf16.h>

typedef float f32x4 __attribute__((ext_vector_type(4)));
typedef short bf16x8 __attribute__((ext_vector_type(8)));
typedef unsigned short u16;
typedef unsigned int u32;

#define NB 32
#define NN 10000
#define DIMX 64

__device__ __forceinline__ u16 f2bf(float f) {
    union { float f; unsigned u; } v; v.f = f;
    unsigned r = (v.u + 0x7FFFu + ((v.u >> 16) & 1u)) >> 16;
    return (u16)r;
}

__device__ __forceinline__ u32 pkbf(float a, float b) {
    __hip_bfloat162 h = __float22bfloat162_rn(make_float2(a, b));
    u32 r; __builtin_memcpy(&r, &h, 4); return r;
}

// LDS-only barrier: drains ds ops (cross-wave LDS visibility) but leaves
// global loads (vmcnt) in flight across the barrier -- unlike __syncthreads,
// which forces vmcnt(0) and kills the x prefetch every iteration.
__device__ __forceinline__ void ldsbar() {
    asm volatile("s_waitcnt lgkmcnt(0)\n\ts_barrier" ::: "memory");
}

// ---------------- K1: prep (ws-packed weights + bias1, vectorized) --------
__global__ void k_prep(const float* __restrict__ x, const float* __restrict__ n2e_w,
                       const float* __restrict__ n2e_b, const float* __restrict__ e2e_w,
                       const int* __restrict__ ip,
                       float* __restrict__ bias1, u16* __restrict__ w1p, u16* __restrict__ w2p) {
    int id = blockIdx.x * 256 + threadIdx.x;
    if (id < 8192) {
        int pair = id >> 1, half = id & 1;
        int b = pair >> 7, j = pair & 127;
        int i = ip[0];
        const f32x4* xr = (const f32x4*)(x + ((size_t)b * NN + i) * DIMX + half * 32);
        const f32x4* w  = (const f32x4*)(n2e_w + j * 128 + 64 + half * 32);
        float s = 0.f;
        #pragma unroll
        for (int kv = 0; kv < 8; ++kv) {
            f32x4 a = xr[kv], bb = w[kv];
            s += a[0] * bb[0] + a[1] * bb[1] + a[2] * bb[2] + a[3] * bb[3];
        }
        s += __shfl_xor(s, 1, 64);
        if (!half) bias1[b * 128 + j] = s + n2e_b[j];
    } else if (id < 16384) {
        int e = id - 8192;
        int i8 = e & 7, lane = (e >> 3) & 63, kk = (e >> 9) & 1, t = e >> 10;
        int row = t * 16 + (lane & 15), col = kk * 32 + (lane >> 4) * 8 + i8;
        w1p[e] = f2bf(n2e_w[row * 128 + col]);
    } else {
        int e = id - 16384;
        int i8 = e & 7, lane = (e >> 3) & 63, kk = (e >> 9) & 3, t = e >> 11;
        int row = t * 16 + (lane & 15), col = kk * 32 + (lane >> 4) * 8 + i8;
        w2p[e] = f2bf(e2e_w[row * 128 + col]);
    }
}

// ---------------- K2: main, t-split GEMM1 + x-through-LDS ----------------
// r16/r17 structure exactly; in-loop barriers are now LDS-only so the x
// prefetch issued at step 2 survives until its use in the NEXT iteration.
__global__ __launch_bounds__(256, 3) void k_main(
        const float* __restrict__ x, const float* __restrict__ adj,
        const float* __restrict__ bias1, const u16* __restrict__ w1p,
        const u16* __restrict__ w2p, const float* __restrict__ e2e_b,
        float* __restrict__ partials) {
    __shared__ u16 sX[8192];      // 16 KB: [par2][sub4][kk2][64][8]
    __shared__ u16 sH1[8192];     // 16 KB: [kk2:4][sub:4][512 u16]
    __shared__ float sBias[128];  // bias1 row b
    __shared__ float sAdj[320];   // chunk adj (zero-padded, 20 subtiles max)

    const int tid = threadIdx.x;
    const int lane = tid & 63, wave = tid >> 6;
    const int c = lane & 15, g = lane >> 4;
    const int bid = blockIdx.x;
    const int b = bid >> 5, qb = bid & 31;
    const int s0 = qb < 17 ? qb * 20 : 340 + (qb - 17) * 19;
    const int cnt = qb < 17 ? 20 : 19;

    if (tid < 128) sBias[tid] = bias1[b * 128 + tid];
    for (int idx = tid; idx < 320; idx += 256)
        sAdj[idx] = (idx < cnt * 16) ? adj[s0 * 16 + idx] : 0.f;

    // W1 fragments for my t-pair {2w, 2w+1} (16 VGPRs, from packed global)
    const bf16x8* const gW1 = (const bf16x8*)w1p;
    const bf16x8 w1a0 = gW1[(wave * 4 + 0) * 64 + lane];
    const bf16x8 w1b0 = gW1[(wave * 4 + 1) * 64 + lane];
    const bf16x8 w1a1 = gW1[(wave * 4 + 2) * 64 + lane];
    const bf16x8 w1b1 = gW1[(wave * 4 + 3) * 64 + lane];
    // W2 fragments for my 2 t2 columns (32 VGPRs)
    const bf16x8* const gW2 = (const bf16x8*)w2p;
    bf16x8 w2r[2][4];
    #pragma unroll
    for (int tt = 0; tt < 2; ++tt)
        #pragma unroll
        for (int kk2 = 0; kk2 < 4; ++kk2)
            w2r[tt][kk2] = gW2[((wave * 2 + tt) * 4 + kk2) * 64 + lane];
    // epilogue bias for my 2 t2 columns (2 regs)
    const float b2v0 = e2e_b[(wave * 2 + 0) * 16 + c];
    const float b2v1 = e2e_b[(wave * 2 + 1) * 16 + c];

    float sAcc[2] = {0.f, 0.f};
    __syncthreads();

    // bias (C-operand) for my t-pair, from LDS after barrier (8 regs)
    const f32x4 cb0 = *(const f32x4*)&sBias[(wave * 2 + 0) * 16 + 4 * g];
    const f32x4 cb1 = *(const f32x4*)&sBias[(wave * 2 + 1) * 16 + 4 * g];

    const size_t xbatch = (size_t)b * NN;
    const int swzW = 16 * (c & 3);
    const int rdOff = (c * 64 + 16 * (g ^ (c & 3))) >> 1;   // u16 units

    // ---- prefetch iteration 0's x for my subtile ----
    f32x4 xl[4];
    {
        int idx = wave;
        int stl = idx < cnt ? idx : cnt - 1;
        const float* xr = x + (xbatch + (s0 + stl) * 16 + c) * 64 + g * 8;
        xl[0] = *(const f32x4*)(xr);
        xl[1] = *(const f32x4*)(xr + 4);
        xl[2] = *(const f32x4*)(xr + 32);
        xl[3] = *(const f32x4*)(xr + 36);
    }

    int par = 0;
    #pragma unroll 1
    for (int it = 0; it < 5; ++it) {
        // ---- 1. convert prefetched x -> sX[par][wave] ----
        #pragma unroll
        for (int kk = 0; kk < 2; ++kk) {
            f32x4 lo = xl[kk * 2], hi = xl[kk * 2 + 1];
            union { bf16x8 v; u32 w[4]; } u;
            u.w[0] = pkbf(lo[0], lo[1]); u.w[1] = pkbf(lo[2], lo[3]);
            u.w[2] = pkbf(hi[0], hi[1]); u.w[3] = pkbf(hi[2], hi[3]);
            *(bf16x8*)&sX[(((par * 4 + wave) * 2 + kk) * 64 + lane) * 8] = u.v;
        }
        // ---- 2. issue next iteration's x loads (stay in flight past bar) ----
        if (it < 4) {
            int idx = (it + 1) * 4 + wave;
            int stl = idx < cnt ? idx : cnt - 1;
            const float* xr = x + (xbatch + (s0 + stl) * 16 + c) * 64 + g * 8;
            xl[0] = *(const f32x4*)(xr);
            xl[1] = *(const f32x4*)(xr + 4);
            xl[2] = *(const f32x4*)(xr + 32);
            xl[3] = *(const f32x4*)(xr + 36);
        }
        ldsbar();   // 3. x visible (LDS-only drain; vmcnt stays outstanding)

        // ---- 4. GEMM1: my t-pair (slice kk2 == wave), all 4 subtiles ----
        u16* const bufW = &sH1[wave * 2048];
        #pragma unroll
        for (int sub = 0; sub < 4; ++sub) {
            bf16x8 A10 = *(const bf16x8*)&sX[(((par * 4 + sub) * 2 + 0) * 64 + lane) * 8];
            bf16x8 A11 = *(const bf16x8*)&sX[(((par * 4 + sub) * 2 + 1) * 64 + lane) * 8];
            f32x4 d0 = __builtin_amdgcn_mfma_f32_16x16x32_bf16(w1a0, A10, cb0, 0, 0, 0);
            d0 = __builtin_amdgcn_mfma_f32_16x16x32_bf16(w1b0, A11, d0, 0, 0, 0);
            f32x4 d1 = __builtin_amdgcn_mfma_f32_16x16x32_bf16(w1a1, A10, cb1, 0, 0, 0);
            d1 = __builtin_amdgcn_mfma_f32_16x16x32_bf16(w1b1, A11, d1, 0, 0, 0);
            u32 p00 = pkbf(fmaxf(d0[0], 0.f), fmaxf(d0[1], 0.f));
            u32 p01 = pkbf(fmaxf(d0[2], 0.f), fmaxf(d0[3], 0.f));
            u32 p10 = pkbf(fmaxf(d1[0], 0.f), fmaxf(d1[1], 0.f));
            u32 p11 = pkbf(fmaxf(d1[2], 0.f), fmaxf(d1[3], 0.f));
            int base = c * 64;
            *(uint2*)&bufW[sub * 512 + ((base + ((8 * g) ^ swzW)) >> 1)]      = make_uint2(p00, p01);
            *(uint2*)&bufW[sub * 512 + ((base + ((32 + 8 * g) ^ swzW)) >> 1)] = make_uint2(p10, p11);
        }
        ldsbar();   // 5. h1 visible (LDS-only drain)

        // ---- 6. GEMM2: all 4 subtiles, my 2 t2 columns ----
        f32x4 acc[4][2];   // 32 AGPRs
        #pragma unroll
        for (int sub = 0; sub < 4; ++sub)
            #pragma unroll
            for (int tt = 0; tt < 2; ++tt) acc[sub][tt] = (f32x4){0.f,0.f,0.f,0.f};
        #pragma unroll
        for (int kk2 = 0; kk2 < 4; ++kk2) {
            bf16x8 A2[4];
            #pragma unroll
            for (int sub = 0; sub < 4; ++sub)
                A2[sub] = *(const bf16x8*)&sH1[kk2 * 2048 + sub * 512 + rdOff];
            #pragma unroll
            for (int tt = 0; tt < 2; ++tt)
                #pragma unroll
                for (int sub = 0; sub < 4; ++sub)
                    acc[sub][tt] = __builtin_amdgcn_mfma_f32_16x16x32_bf16(A2[sub], w2r[tt][kk2], acc[sub][tt], 0, 0, 0);
        }

        // ---- 7. epilogue: adj + bias2 + relu, weighted row sum ----
        #pragma unroll
        for (int sub = 0; sub < 4; ++sub) {
            f32x4 av = *(const f32x4*)&sAdj[(it * 4 + sub) * 16 + 4 * g];
            #pragma unroll
            for (int r = 0; r < 4; ++r) {
                sAcc[0] = fmaf(av[r], fmaxf(acc[sub][0][r] + b2v0, 0.f), sAcc[0]);
                sAcc[1] = fmaf(av[r], fmaxf(acc[sub][1][r] + b2v1, 0.f), sAcc[1]);
            }
        }
        par ^= 1;
    }

    // ---- reduce over lane-groups (g); direct partials write ----
    float red[2];
    #pragma unroll
    for (int tt = 0; tt < 2; ++tt) {
        float v = sAcc[tt];
        v += __shfl_xor(v, 16, 64);
        v += __shfl_xor(v, 32, 64);
        red[tt] = v;
    }
    if (lane < 16) {
        #pragma unroll
        for (int tt = 0; tt < 2; ++tt)
            partials[bid * 128 + (wave * 2 + tt) * 16 + lane] = red[tt];
    }
}

// ---------------- K3: final small MLP (256 threads, 2-way split dots) -----
__global__ void k_final(const float* __restrict__ partials, const float* __restrict__ x,
                        const int* __restrict__ ip,
                        const float* __restrict__ e2n_w, const float* __restrict__ e2n_b,
                        const float* __restrict__ n2n_w, const float* __restrict__ n2n_b,
                        const float* __restrict__ out_w, const float* __restrict__ out_b,
                        float* __restrict__ out) {
    int b = blockIdx.x, t = threadIdx.x;
    int j = t >> 1, half = t & 1;
    __shared__ float s0[128], s1[128], s2[128];

    float a0 = 0.f;
    #pragma unroll
    for (int q = 0; q < 16; ++q)
        a0 += partials[(b * 32 + half * 16 + q) * 128 + j];
    a0 += __shfl_xor(a0, 1, 64);
    if (!half) s0[j] = a0;
    __syncthreads();
    {
        const f32x4* w  = (const f32x4*)(e2n_w + j * 128 + half * 64);
        const f32x4* sv = (const f32x4*)(s0 + half * 64);
        float a1 = 0.f;
        #pragma unroll
        for (int k = 0; k < 16; ++k) {
            f32x4 wv = w[k], s4 = sv[k];
            a1 += wv[0] * s4[0] + wv[1] * s4[1] + wv[2] * s4[2] + wv[3] * s4[3];
        }
        a1 += __shfl_xor(a1, 1, 64);
        if (!half) s1[j] = fmaxf(a1 + e2n_b[j], 0.f);
    }
    __syncthreads();
    {
        const f32x4* w  = (const f32x4*)(n2n_w + j * 128 + half * 64);
        const f32x4* sv = (const f32x4*)(s1 + half * 64);
        float a2 = 0.f;
        #pragma unroll
        for (int k = 0; k < 16; ++k) {
            f32x4 wv = w[k], s4 = sv[k];
            a2 += wv[0] * s4[0] + wv[1] * s4[1] + wv[2] * s4[2] + wv[3] * s4[3];
        }
        a2 += __shfl_xor(a2, 1, 64);
        if (!half) s2[j] = fmaxf(a2 + n2n_b[j], 0.f);
    }
    __syncthreads();
    if (j < 64) {
        int i = ip[0];
        const float* xr = x + ((size_t)b * NN + i) * DIMX;
        const float* ow = out_w + j * 192;
        float o = 0.f;
        if (!half) {
            #pragma unroll 8
            for (int m = 0; m < 64; ++m) o += ow[m] * xr[m];
            #pragma unroll 8
            for (int m = 0; m < 32; ++m) o += ow[64 + m] * s2[m];
        } else {
            #pragma unroll 8
            for (int m = 32; m < 128; ++m) o += ow[64 + m] * s2[m];
        }
        o += __shfl_xor(o, 1, 64);
        if (!half) out[b * 64 + j] = o + out_b[j];
    }
}

extern "C" void kernel_launch(void* const* d_in, const int* in_sizes, int n_in,
                              void* d_out, int out_size, void* d_ws, size_t ws_size,
                              hipStream_t stream) {
    const float* x      = (const float*)d_in[0];
    const float* adj    = (const float*)d_in[1];
    const float* n2e_w  = (const float*)d_in[2];
    const float* n2e_b  = (const float*)d_in[3];
    const float* e2e_w  = (const float*)d_in[4];
    const float* e2e_b  = (const float*)d_in[5];
    const float* e2n_w  = (const float*)d_in[6];
    const float* e2n_b  = (const float*)d_in[7];
    const float* n2n_w  = (const float*)d_in[8];
    const float* n2n_b  = (const float*)d_in[9];
    const float* out_w  = (const float*)d_in[10];
    const float* out_b  = (const float*)d_in[11];
    const int*   ip     = (const int*)d_in[12];
    float* out = (float*)d_out;

    char* ws = (char*)d_ws;
    float* bias1    = (float*)ws;               // 16384 B
    u16*   w1p      = (u16*)(ws + 16384);       // 16384 B
    u16*   w2p      = (u16*)(ws + 32768);       // 32768 B
    float* partials = (float*)(ws + 65536);     // 524288 B (1024 blocks * 128 f32)

    k_prep<<<128, 256, 0, stream>>>(x, n2e_w, n2e_b, e2e_w, ip, bias1, w1p, w2p);
    k_main<<<1024, 256, 0, stream>>>(x, adj, bias1, w1p, w2p, e2e_b, partials);
    k_final<<<32, 256, 0, stream>>>(partials, x, ip, e2n_w, e2n_b, n2n_w, n2n_b,
                                    out_w, out_b, out);
}